// Round 2
// baseline (281.956 us; speedup 1.0000x reference)
//
#include <hip/hip_runtime.h>
#include <hip/hip_bf16.h>

typedef __attribute__((ext_vector_type(8))) short bf16x8;
typedef __attribute__((ext_vector_type(4))) short bf16x4;
typedef __attribute__((ext_vector_type(4))) float f32x4;

// ws layout (bytes):
//   WTf  [36 ct][6 ks][64 ln][8] bf16 @ 0       (221184 B)  fragment-major [Wq|Wk|Wv]
//   WfcTf[12 ct][6 ks][64 ln][8] bf16 @ 221184  (73728 B)
//   biasT[3][49 k][49 q] f32        @ 294912    (28812 B)   0=plain 1=+LOWER 2=+RIGHT

__device__ __forceinline__ short f2bf(float f) {
  unsigned u = __float_as_uint(f);
  unsigned r = (u + 0x7FFFu + ((u >> 16) & 1u)) >> 16;
  return (short)(unsigned short)r;
}
// LDS anti-bank-conflict swizzle on flat short index: byte bits[6:4] ^= byte bits[9:7].
// Stays within each 64-short chunk; preserves 8-short (16B) block contiguity.
__device__ __forceinline__ int swz(int f) { return f ^ (((f >> 6) & 7) << 3); }

__global__ void prep_kernel(const float* __restrict__ Wq, const float* __restrict__ Wk,
                            const float* __restrict__ Wv, const float* __restrict__ Wfc,
                            const float* __restrict__ pos,
                            short* __restrict__ WTf, short* __restrict__ WfcTf,
                            float* __restrict__ biasT) {
  int i0 = blockIdx.x * blockDim.x + threadIdx.x;
  int stride = gridDim.x * blockDim.x;
  // WTf fragment-major: lane ln reads 8 bf16 at [ct][ks][ln]: col=ct*16+(ln&15),
  // k = ks*32 + (ln>>4)*8 + e
  for (int o = i0; o < 110592; o += stride) {
    int e = o & 7, ln = (o >> 3) & 63, t = o >> 9;
    int ks = t % 6, ct = t / 6;
    int col = ct * 16 + (ln & 15);
    int k = ks * 32 + ((ln >> 4) << 3) + e;
    const float* W = (col < 192) ? Wq : (col < 384) ? Wk : Wv;
    WTf[o] = f2bf(W[k * 192 + (col % 192)]);
  }
  for (int o = i0; o < 36864; o += stride) {
    int e = o & 7, ln = (o >> 3) & 63, t = o >> 9;
    int ks = t % 6, ct = t / 6;
    int col = ct * 16 + (ln & 15);
    int k = ks * 32 + ((ln >> 4) << 3) + e;
    WfcTf[o] = f2bf(Wfc[k * 192 + col]);
  }
  // transposed bias: biasT[t][k*49 + q] = bias(q,k)  (masks are symmetric in q,k)
  for (int idx = i0; idx < 3 * 2401; idx += stride) {
    int t = idx / 2401, r = idx - t * 2401;
    int kk = r / 49, q = r - kk * 49;
    int ri = kk / 7 - q / 7 + 6;
    int rj = kk % 7 - q % 7 + 6;
    float v = pos[ri * 13 + rj];
    if (t == 1 && ((q >= 28) != (kk >= 28))) v = -1e30f;
    if (t == 2 && ((q % 7 >= 4) != (kk % 7 >= 4))) v = -1e30f;
    biasT[idx] = v;
  }
}

__launch_bounds__(384, 3)
__global__ void swin_fused(const float* __restrict__ x,
                           const short* __restrict__ WTf,
                           const short* __restrict__ WfcTf,
                           const float* __restrict__ biasT,
                           const float* __restrict__ bfc,
                           float* __restrict__ out) {
  // LDS: (9408 + 9408 + 12288) * 2 = 62208 B  -> 2 blocks/CU
  __shared__ short qf[9408];      // q[49][192] flat (swizzled); reused for attn-out
  __shared__ short kf[9408];      // k[49][192] flat (swizzled)
  __shared__ short vT[12288];     // per-window v^T: [6][32 d][64 tok] (swizzled), tok-padded 0

  const int bid = blockIdx.x;
  const int b = bid >> 6;
  const int g = bid & 63;
  const int tid = threadIdx.x;
  const int wave = tid >> 6;
  const int lane = tid & 63;
  const int lrow = lane & 15;            // within-tile row/col
  const int lk8 = (lane >> 4) << 3;      // k-chunk base {0,8,16,24}
  const int lg4 = (lane >> 4) << 2;      // D-frag row base {0,4,8,12}

  const bf16x8 z8 = {0, 0, 0, 0, 0, 0, 0, 0};
  const f32x4 z4 = {0.f, 0.f, 0.f, 0.f};

  for (int i = tid; i < 12288; i += 384) vT[i] = 0;   // zero pad (swizzle-safe: full clear)
  __syncthreads();

  // ---------------- Phase 1: QKV = x_shifted(49 tok) @ [Wq|Wk|Wv]  (M=64pad,N=576,K=192)
  bf16x8 afrag[4][6];
  #pragma unroll
  for (int mt = 0; mt < 4; ++mt) {
    int row = mt * 16 + lrow;
    if (row < 49) {
      int t = g * 49 + row;
      int h = t / 56, w = t - h * 56;
      int hs = h + 3; if (hs >= 56) hs -= 56;        // roll(-3)
      int ws2 = w + 3; if (ws2 >= 56) ws2 -= 56;
      const float* xr = x + ((b * 56 + hs) * 56 + ws2) * 192;
      #pragma unroll
      for (int ks = 0; ks < 6; ++ks) {
        const float* p = xr + 32 * ks + lk8;
        float4 f0 = *(const float4*)(p);
        float4 f1 = *(const float4*)(p + 4);
        bf16x8 a;
        a[0] = f2bf(f0.x); a[1] = f2bf(f0.y); a[2] = f2bf(f0.z); a[3] = f2bf(f0.w);
        a[4] = f2bf(f1.x); a[5] = f2bf(f1.y); a[6] = f2bf(f1.z); a[7] = f2bf(f1.w);
        afrag[mt][ks] = a;
      }
    } else {
      #pragma unroll
      for (int ks = 0; ks < 6; ++ks) afrag[mt][ks] = z8;
    }
  }

  #pragma unroll 1
  for (int nt = 0; nt < 6; ++nt) {
    const short* wr = WTf + ((wave * 6 + nt) * 6) * 512 + (lane << 3);  // coalesced 1KB/wave
    f32x4 acc[4] = {z4, z4, z4, z4};
    #pragma unroll
    for (int ks = 0; ks < 6; ++ks) {
      bf16x8 bfrag = *(const bf16x8*)(wr + ks * 512);
      #pragma unroll
      for (int mt = 0; mt < 4; ++mt)
        acc[mt] = __builtin_amdgcn_mfma_f32_16x16x32_bf16(afrag[mt][ks], bfrag, acc[mt], 0, 0, 0);
    }
    int col = wave * 96 + nt * 16 + lrow;            // 0..575
    #pragma unroll
    for (int mt = 0; mt < 4; ++mt) {
      #pragma unroll
      for (int jj = 0; jj < 4; ++jj) {
        int rowD = mt * 16 + lg4 + jj;
        if (rowD < 49) {
          short v = f2bf(acc[mt][jj]);
          if (col < 192) {
            qf[swz(rowD * 192 + col)] = v;
          } else if (col < 384) {
            kf[swz(rowD * 192 + col - 192)] = v;
          } else {
            int flat = rowD * 192 + col - 384;       // position in [49][192] v-flat
            int win2 = flat / 1568;
            int rem = flat - win2 * 1568;
            vT[swz((win2 * 32 + (rem & 31)) * 64 + (rem >> 5))] = v;
          }
        }
      }
    }
  }
  __syncthreads();

  // ---------------- Phase 2: attention, wave j owns window j. Swapped QK^T:
  // S^T = mfma(K, Q) so lane regs hold P^T in the B-layout of a K=16 MFMA.
  const int j = wave;
  const int qbase = j * 1568;
  {
    bf16x8 ka[4], qb[4];
    #pragma unroll
    for (int t = 0; t < 4; ++t) {
      int row = t * 16 + lrow;
      ka[t] = (row < 49) ? *(const bf16x8*)(kf + swz(qbase + row * 32 + lk8)) : z8;
      qb[t] = (row < 49) ? *(const bf16x8*)(qf + swz(qbase + row * 32 + lk8)) : z8;
    }
    f32x4 st[4][4];   // st[kt][qt]: S^T[k = kt*16+lg4+jj][q = qt*16+lrow]
    #pragma unroll
    for (int kt = 0; kt < 4; ++kt)
      #pragma unroll
      for (int qt = 0; qt < 4; ++qt)
        st[kt][qt] = __builtin_amdgcn_mfma_f32_16x16x32_bf16(ka[kt], qb[qt], z4, 0, 0, 0);

    int win = (g * 6 + j) & 63;
    const float* bt = biasT + ((win >= 56) ? 2401 : (win == 7) ? 4802 : 0);
    #pragma unroll
    for (int kt = 0; kt < 4; ++kt)
      #pragma unroll
      for (int jj = 0; jj < 4; ++jj) {
        int kk = kt * 16 + lg4 + jj;
        #pragma unroll
        for (int qt = 0; qt < 4; ++qt) {
          int qq = qt * 16 + lrow;
          st[kt][qt][jj] = (kk < 49 && qq < 49)
              ? st[kt][qt][jj] * 5.65685424949238f + bt[kk * 49 + qq]   // *sqrt(32)
              : -1e30f;
        }
      }

    // register softmax over k for each q-column, + pack P^T to bf16 B-frags
    bf16x4 pb[4][4];
    #pragma unroll
    for (int qt = 0; qt < 4; ++qt) {
      float m = -1e30f;
      #pragma unroll
      for (int kt = 0; kt < 4; ++kt)
        #pragma unroll
        for (int jj = 0; jj < 4; ++jj)
          m = fmaxf(m, st[kt][qt][jj]);
      m = fmaxf(m, __shfl_xor(m, 16));
      m = fmaxf(m, __shfl_xor(m, 32));
      float sum = 0.f;
      #pragma unroll
      for (int kt = 0; kt < 4; ++kt)
        #pragma unroll
        for (int jj = 0; jj < 4; ++jj) {
          float e = __expf(st[kt][qt][jj] - m);
          st[kt][qt][jj] = e;
          sum += e;
        }
      sum += __shfl_xor(sum, 16);
      sum += __shfl_xor(sum, 32);
      float inv = 1.0f / sum;
      #pragma unroll
      for (int kt = 0; kt < 4; ++kt) {
        bf16x4 p = {f2bf(st[kt][qt][0] * inv), f2bf(st[kt][qt][1] * inv),
                    f2bf(st[kt][qt][2] * inv), f2bf(st[kt][qt][3] * inv)};
        pb[kt][qt] = p;
      }
    }

    // PV: O^T[d][q] = sum_k V^T[d][k] * P^T[k][q], 4 k-tiles of 16
    f32x4 o[2][4] = {{z4, z4, z4, z4}, {z4, z4, z4, z4}};
    #pragma unroll
    for (int dt = 0; dt < 2; ++dt)
      #pragma unroll
      for (int kt = 0; kt < 4; ++kt) {
        bf16x4 va = *(const bf16x4*)(vT + swz((j * 32 + dt * 16 + lrow) * 64 + kt * 16 + lg4));
#if __has_builtin(__builtin_amdgcn_mfma_f32_16x16x16bf16_1k)
        #pragma unroll
        for (int qt = 0; qt < 4; ++qt)
          o[dt][qt] = __builtin_amdgcn_mfma_f32_16x16x16bf16_1k(va, pb[kt][qt], o[dt][qt], 0, 0, 0);
#else
        // padded K=32 fallback: both operands put the 4 real k-values at e=0..3 of each chunk
        bf16x8 va8 = {va[0], va[1], va[2], va[3], 0, 0, 0, 0};
        #pragma unroll
        for (int qt = 0; qt < 4; ++qt) {
          bf16x8 pb8 = {pb[kt][qt][0], pb[kt][qt][1], pb[kt][qt][2], pb[kt][qt][3], 0, 0, 0, 0};
          o[dt][qt] = __builtin_amdgcn_mfma_f32_16x16x32_bf16(va8, pb8, o[dt][qt], 0, 0, 0);
        }
#endif
      }

    // attn-out overwrites q region (same flat positions). Safe: qb consumed via reg deps.
    #pragma unroll
    for (int qt = 0; qt < 4; ++qt) {
      int qq = qt * 16 + lrow;
      if (qq < 49) {
        #pragma unroll
        for (int dt = 0; dt < 2; ++dt)
          #pragma unroll
          for (int jj = 0; jj < 4; ++jj) {
            int d = dt * 16 + lg4 + jj;
            qf[swz(qbase + qq * 32 + d)] = f2bf(o[dt][qt][jj]);
          }
      }
    }
  }
  __syncthreads();

  // ---------------- Phase 3: out = attnout[49][192] @ Wfc + bfc, inverse roll
  bf16x8 oa[4][6];
  #pragma unroll
  for (int mt = 0; mt < 4; ++mt) {
    int row = mt * 16 + lrow;
    #pragma unroll
    for (int ks = 0; ks < 6; ++ks)
      oa[mt][ks] = (row < 49) ? *(const bf16x8*)(qf + swz(row * 192 + ks * 32 + lk8)) : z8;
  }
  #pragma unroll 1
  for (int nt = 0; nt < 2; ++nt) {
    const short* wr = WfcTf + ((wave * 2 + nt) * 6) * 512 + (lane << 3);
    f32x4 acc[4] = {z4, z4, z4, z4};
    #pragma unroll
    for (int ks = 0; ks < 6; ++ks) {
      bf16x8 bfrag = *(const bf16x8*)(wr + ks * 512);
      #pragma unroll
      for (int mt = 0; mt < 4; ++mt)
        acc[mt] = __builtin_amdgcn_mfma_f32_16x16x32_bf16(oa[mt][ks], bfrag, acc[mt], 0, 0, 0);
    }
    int col = wave * 32 + nt * 16 + lrow;            // 0..191
    float bias = bfc[col];
    #pragma unroll
    for (int mt = 0; mt < 4; ++mt)
      #pragma unroll
      for (int jj = 0; jj < 4; ++jj) {
        int qr = mt * 16 + lg4 + jj;
        if (qr < 49) {
          int t = g * 49 + qr;
          int h = t / 56, w = t - h * 56;
          int hd = h + 3; if (hd >= 56) hd -= 56;    // roll(+3)
          int wd = w + 3; if (wd >= 56) wd -= 56;
          out[(size_t)((b * 56 + hd) * 56 + wd) * 192 + col] = acc[mt][jj] + bias;
        }
      }
  }
}

extern "C" void kernel_launch(void* const* d_in, const int* in_sizes, int n_in,
                              void* d_out, int out_size, void* d_ws, size_t ws_size,
                              hipStream_t stream) {
  const float* x   = (const float*)d_in[0];
  const float* Wq  = (const float*)d_in[1];
  const float* Wk  = (const float*)d_in[2];
  const float* Wv  = (const float*)d_in[3];
  const float* Wfc = (const float*)d_in[4];
  const float* bfc = (const float*)d_in[5];
  const float* pos = (const float*)d_in[6];

  short* WTf   = (short*)d_ws;
  short* WfcTf = (short*)((char*)d_ws + 221184);
  float* biasT = (float*)((char*)d_ws + 294912);

  hipLaunchKernelGGL(prep_kernel, dim3(128), dim3(256), 0, stream,
                     Wq, Wk, Wv, Wfc, pos, WTf, WfcTf, biasT);
  hipLaunchKernelGGL(swin_fused, dim3(2048), dim3(384), 0, stream,
                     x, WTf, WfcTf, biasT, bfc, (float*)d_out);
}